// Round 3
// baseline (378.686 us; speedup 1.0000x reference)
//
#include <hip/hip_runtime.h>
#include <hip/hip_bf16.h>

// GCN: 3x (GEMM + D^-1/2 (A+I) D^-1/2 aggregation) + log_softmax.
// R13: fusion de-risked. Two container failures with R11's restructured
//      gather (cause indistinguishable: infra vs kernel-kill). This round
//      keeps R10's PROVEN 32-lane pair gather byte-identical (61.5us,
//      request-bound) and adds only a minimal MFMA epilogue: W^T staged
//      swizzled at block start (hidden under gather), 8 finished rows ->
//      swizzled LDS A-tile (rows 8..15 zeroed; XOR swizzle maps the two
//      row-sets disjointly), one barrier, 8/4 MFMAs/wave, store
//      H_next*dinv. Eliminates gemm2/gemm3 + 2x(25.6MB write+read).

constexpr int N_NODES = 100000;
constexpr int E_EDGES = 1600000;
constexpr int NB = (N_NODES + 127) / 128;   // 782 coarse buckets
constexpr int BCAP = 2560;                  // bucket cap (mean 2048, sd 45)
constexpr int CHUNK = 4096;
constexpr int NCHUNK = (E_EDGES + CHUNK - 1) / CHUNK;  // 391

typedef short bf16x8 __attribute__((ext_vector_type(8)));
typedef float f32x4 __attribute__((ext_vector_type(4)));

// ---------------- helpers ---------------------------------------------------
__device__ __forceinline__ unsigned short f2bf(float f) {   // RNE fp32->bf16
    unsigned u = __float_as_uint(f);
    unsigned r = (u + 0x7fff + ((u >> 16) & 1)) >> 16;
    return (unsigned short)r;
}
__device__ __forceinline__ float bf_lo(unsigned u) { return __uint_as_float(u << 16); }
__device__ __forceinline__ float bf_hi(unsigned u) { return __uint_as_float(u & 0xffff0000u); }
__device__ __forceinline__ unsigned pack2bf(float lo, float hi) {
    return (unsigned)f2bf(lo) | ((unsigned)f2bf(hi) << 16);
}

__device__ __forceinline__ int get_idx(const void* ei, int use64, long long pos) {
    if (use64) return (int)((const long long*)ei)[pos];
    return ((const int*)ei)[pos];
}

// ---------------- W^T prep + detect + cursor zero (block 3) ----------------
__global__ void prep_wt_kernel(const float* __restrict__ W1, const float* __restrict__ W2,
                               const float* __restrict__ W3,
                               unsigned short* __restrict__ WT1,
                               unsigned short* __restrict__ WT2,
                               unsigned short* __restrict__ WT3,
                               const int* __restrict__ ei32, int* __restrict__ flag,
                               int* __restrict__ cursorPad) {
    const int b = blockIdx.x;
    if (b == 3) {
        for (int i = threadIdx.x; i < NB * 16; i += blockDim.x) cursorPad[i] = 0;
        if (threadIdx.x == 0) {
            int ok64 = 1;
#pragma unroll
            for (int i = 1; i < 64; i += 2) ok64 &= (ei32[i] == 0);
            *flag = ok64;
        }
        return;
    }
    const float* W = (b == 0) ? W1 : (b == 1) ? W2 : W3;
    unsigned short* WT = (b == 0) ? WT1 : (b == 1) ? WT2 : WT3;
    const int COUT = (b == 2) ? 64 : 128;
    for (int i = threadIdx.x; i < COUT * 128; i += blockDim.x) {
        int c = i >> 7;
        int k = i & 127;
        WT[c * 128 + k] = f2bf(W[k * COUT + c]);
    }
}

// ---------------- P1: single-pass scatter into fixed-capacity buckets ------
__global__ __launch_bounds__(256) void scatter_direct(
    const void* __restrict__ ei, const int* __restrict__ flag,
    int* __restrict__ cursorPad, unsigned* __restrict__ pairs) {
    __shared__ int h[NB];
    __shared__ int base[NB];
    __shared__ unsigned dstb[CHUNK];
    const int t = threadIdx.x;
    const int use64 = *flag;
    const int e0 = blockIdx.x * CHUNK;
    const int e1 = min(E_EDGES, e0 + CHUNK);

    for (int i = t; i < NB; i += 256) h[i] = 0;
    __syncthreads();
    for (int e = e0 + t; e < e1; e += 256) {
        unsigned d = (unsigned)get_idx(ei, use64, (long long)E_EDGES + e);
        dstb[e - e0] = d;
        atomicAdd(&h[d >> 7], 1);
    }
    __syncthreads();
    for (int i = t; i < NB; i += 256) {
        int c = h[i];
        if (c) base[i] = atomicAdd(&cursorPad[i * 16], c);
        h[i] = 0;
    }
    __syncthreads();
    for (int e = e0 + t; e < e1; e += 256) {
        unsigned s = (unsigned)get_idx(ei, use64, e);
        unsigned d = dstb[e - e0];
        int b = d >> 7;
        int r = base[b] + atomicAdd(&h[b], 1);
        if (r < BCAP) pairs[(unsigned)b * BCAP + r] = (s << 7) | (d & 127u);
    }
}

// ---------------- P2: per-bucket fine counting sort ------------------------
__global__ __launch_bounds__(256) void fine_sort_kernel(
    const unsigned* __restrict__ pairs, const int* __restrict__ cursorPad,
    int* __restrict__ csr, int* __restrict__ rowptr, int* __restrict__ deg,
    float* __restrict__ dinv) {
    __shared__ int h[128];
    __shared__ int rp[128];
    __shared__ int sc[128];
    const int t = threadIdx.x;
    const int b = blockIdx.x;
    const int base = b * BCAP;
    const int cnt = min(cursorPad[b * 16], BCAP);

    if (t < 128) h[t] = 0;
    __syncthreads();
    for (int i = t; i < cnt; i += 256) {
        unsigned p = pairs[base + i];
        atomicAdd(&h[p & 127u], 1);
    }
    __syncthreads();
    int v = (t < 128) ? h[t] : 0;
    if (t < 128) sc[t] = v;
    __syncthreads();
    int incl = v;
    for (int off = 1; off < 128; off <<= 1) {
        int add = (t >= off && t < 128) ? sc[t - off] : 0;
        __syncthreads();
        if (t < 128) {
            incl += add;
            sc[t] = incl;
        }
        __syncthreads();
    }
    if (t < 128) {
        rp[t] = incl - v;
        int node = b * 128 + t;
        if (node < N_NODES) {
            rowptr[node] = base + incl - v;
            deg[node] = v;
            dinv[node] = rsqrtf((float)(v + 1));
        }
        h[t] = 0;
    }
    __syncthreads();
    for (int i = t; i < cnt; i += 256) {
        unsigned p = pairs[base + i];
        int l = (int)(p & 127u);
        int r = atomicAdd(&h[l], 1);
        csr[base + rp[l] + r] = (int)(p >> 7);
    }
}

// ---------------- MFMA GEMM, fp32 input, XOR-swizzled LDS (layer 1) --------
// A slot (16B units): ((m>>4)*16 + k8)*16 + ((m&15) ^ k8)   [write 2-way]
// W slot:             (k8*COUT + ct*16 + (n16 ^ k8))        [write 2-way]
template <int COUT>
__global__ __launch_bounds__(256) void gemm_mfma_f32(const float* __restrict__ X,
                                                     const unsigned short* __restrict__ WT,
                                                     const float* __restrict__ dinv,
                                                     unsigned short* __restrict__ H) {
    constexpr int NT = COUT / 16;
    __shared__ short Albs[64 * 128];
    __shared__ short Wlds[COUT * 128];

    const int t = threadIdx.x;
    const int row0 = blockIdx.x * 64;

    for (int i = t; i < COUT * 16; i += 256) {
        int n = i >> 4, k8 = i & 15;
        bf16x8 v = *(const bf16x8*)&WT[n * 128 + k8 * 8];
        int ns = (n & ~15) | ((n & 15) ^ k8);
        *(bf16x8*)&Wlds[(k8 * COUT + ns) * 8] = v;
    }
    for (int i = t; i < 1024; i += 256) {
        int m = i >> 4, k8 = i & 15;
        int gr = min(row0 + m, N_NODES - 1);
        const float* p = &X[(size_t)gr * 128 + k8 * 8];
        float4 f0 = *(const float4*)p;
        float4 f1 = *(const float4*)(p + 4);
        bf16x8 v;
        v[0] = (short)f2bf(f0.x); v[1] = (short)f2bf(f0.y);
        v[2] = (short)f2bf(f0.z); v[3] = (short)f2bf(f0.w);
        v[4] = (short)f2bf(f1.x); v[5] = (short)f2bf(f1.y);
        v[6] = (short)f2bf(f1.z); v[7] = (short)f2bf(f1.w);
        int u = ((m >> 4) * 16 + k8) * 16 + ((m & 15) ^ k8);
        *(bf16x8*)&Albs[u * 8] = v;
    }
    __syncthreads();

    const int lane = t & 63;
    const int wv = t >> 6;
    const int l15 = lane & 15;
    const int quad = lane >> 4;

    f32x4 acc[NT];
#pragma unroll
    for (int ct = 0; ct < NT; ct++) acc[ct] = (f32x4){0.f, 0.f, 0.f, 0.f};

#pragma unroll
    for (int kcg = 0; kcg < 4; kcg++) {
        const int k8 = kcg * 4 + quad;
        bf16x8 a = *(const bf16x8*)&Albs[((wv * 16 + k8) * 16 + (l15 ^ k8)) * 8];
#pragma unroll
        for (int ct = 0; ct < NT; ct++) {
            bf16x8 b = *(const bf16x8*)&Wlds[(k8 * COUT + ct * 16 + (l15 ^ k8)) * 8];
            acc[ct] = __builtin_amdgcn_mfma_f32_16x16x32_bf16(a, b, acc[ct], 0, 0, 0);
        }
    }

    const int m0 = row0 + wv * 16;
#pragma unroll
    for (int r = 0; r < 4; r++) {
        int m = m0 + quad * 4 + r;
        if (m < N_NODES) {
            float dv = dinv[m];
#pragma unroll
            for (int ct = 0; ct < NT; ct++)
                H[(size_t)m * COUT + ct * 16 + l15] = f2bf(acc[ct][r] * dv);
        } else if (m == N_NODES) {
#pragma unroll
            for (int ct = 0; ct < NT; ct++)
                H[(size_t)m * COUT + ct * 16 + l15] = 0;
        }
    }
}

// ---------------- fused: R10 pair aggregation (128ch) + next-layer GEMM ----
// Gather body is byte-identical to R10's proven aggregate128_pair (8 nodes
// per 256-thread block, 32-lane halves, uint2). New code is only the
// epilogue: bias+relu -> swizzled 16-row A-tile (rows 8..15 zero) ->
// 16x128 @ 128xCOUT MFMA -> Hn = result * dinv.
template <int COUT>
__global__ __launch_bounds__(256) void agg128_fused(
    const unsigned short* __restrict__ Hb, const int* __restrict__ rowptr,
    const int* __restrict__ deg, const int* __restrict__ csr,
    const float* __restrict__ dinv, const float* __restrict__ bias,
    const unsigned short* __restrict__ WT, unsigned short* __restrict__ Hn) {
    constexpr int NT = COUT / 16;   // 8 or 4 column tiles
    constexpr int CTW = NT / 4;     // ct per wave: 2 or 1
    __shared__ short Wlds[COUT * 128];
    __shared__ short Atile[16 * 128];

    const int t = threadIdx.x;

    // stage W^T (L2-hot) swizzled; consumed only after the barrier
    for (int i = t; i < COUT * 16; i += 256) {
        int nn = i >> 4, k8 = i & 15;
        bf16x8 v = *(const bf16x8*)&WT[nn * 128 + k8 * 8];
        int ns = (nn & ~15) | ((nn & 15) ^ k8);
        *(bf16x8*)&Wlds[(k8 * COUT + ns) * 8] = v;
    }
    // zero A-tile rows 8..15 (XOR swizzle keeps row-sets 0..7 / 8..15 in
    // disjoint slots, so no overlap with the live writes below)
    if (t < 128) {
        int k8z = t >> 3, mm = 8 + (t & 7);
        *(uint4*)&Atile[(k8z * 16 + (mm ^ k8z)) * 8] = (uint4){0u, 0u, 0u, 0u};
    }

    // ---- R10 gather (proven) ----
    const int lane = t & 63;
    const int wv = t >> 6;
    const int li = lane & 31;
    const int half = lane >> 5;
    const int n = blockIdx.x * 8 + wv * 2 + half;   // N % 8 == 0
    const unsigned li8 = (unsigned)li * 8u;
    const char* Hc = (const char*)Hb;

    uint2 s = *(const uint2*)(Hc + (size_t)n * 256u + li8);  // self loop
    float a0 = bf_lo(s.x), a1 = bf_hi(s.x), a2 = bf_lo(s.y), a3 = bf_hi(s.y);

    const int start = rowptr[n];
    const int dc = deg[n];
    const int dmax = max(dc, __shfl_xor(dc, 32));

    for (int eb = 0; eb < dmax; eb += 32) {
        int myidx = N_NODES;                     // pad row (zeros)
        if (eb + li < dc) myidx = csr[start + eb + li];
        const int jmax = min(32, dmax - eb);
        int j = 0;
        for (; j + 16 <= jmax; j += 16) {
            int idx[16];
            uint2 u[16];
#pragma unroll
            for (int q = 0; q < 16; q++) idx[q] = __shfl(myidx, j + q, 32);
#pragma unroll
            for (int q = 0; q < 16; q++)
                u[q] = *(const uint2*)(Hc + (((unsigned)idx[q] << 8) + li8));
#pragma unroll
            for (int q = 0; q < 16; q++) {
                a0 += bf_lo(u[q].x); a1 += bf_hi(u[q].x);
                a2 += bf_lo(u[q].y); a3 += bf_hi(u[q].y);
            }
        }
        for (; j + 8 <= jmax; j += 8) {
            int idx[8];
            uint2 u[8];
#pragma unroll
            for (int q = 0; q < 8; q++) idx[q] = __shfl(myidx, j + q, 32);
#pragma unroll
            for (int q = 0; q < 8; q++)
                u[q] = *(const uint2*)(Hc + (((unsigned)idx[q] << 8) + li8));
#pragma unroll
            for (int q = 0; q < 8; q++) {
                a0 += bf_lo(u[q].x); a1 += bf_hi(u[q].x);
                a2 += bf_lo(u[q].y); a3 += bf_hi(u[q].y);
            }
        }
        for (; j + 4 <= jmax; j += 4) {
            int idx[4];
            uint2 u[4];
#pragma unroll
            for (int q = 0; q < 4; q++) idx[q] = __shfl(myidx, j + q, 32);
#pragma unroll
            for (int q = 0; q < 4; q++)
                u[q] = *(const uint2*)(Hc + (((unsigned)idx[q] << 8) + li8));
#pragma unroll
            for (int q = 0; q < 4; q++) {
                a0 += bf_lo(u[q].x); a1 += bf_hi(u[q].x);
                a2 += bf_lo(u[q].y); a3 += bf_hi(u[q].y);
            }
        }
        for (; j < jmax; j++) {
            int i0 = __shfl(myidx, j, 32);
            uint2 u0 = *(const uint2*)(Hc + (((unsigned)i0 << 8) + li8));
            a0 += bf_lo(u0.x); a1 += bf_hi(u0.x);
            a2 += bf_lo(u0.y); a3 += bf_hi(u0.y);
        }
    }

    // ---- epilogue: bias+relu -> swizzled A-tile row r, cols 4li..4li+3 ----
    {
        const float dn = dinv[n];
        float4 bv = *(const float4*)((const char*)bias + li * 16);
        unsigned w0 = pack2bf(fmaxf(a0 * dn + bv.x, 0.f), fmaxf(a1 * dn + bv.y, 0.f));
        unsigned w1 = pack2bf(fmaxf(a2 * dn + bv.z, 0.f), fmaxf(a3 * dn + bv.w, 0.f));
        const int r = wv * 2 + half;     // 0..7
        const int k8 = li >> 1;          // slot column group
        uint2 o; o.x = w0; o.y = w1;
        *(uint2*)&Atile[(k8 * 16 + (r ^ k8)) * 8 + (li & 1) * 4] = o;
    }
    __syncthreads();

    // ---- 16x128 @ 128xCOUT (rows 8..15 zero); wave wv owns ct=wv*CTW.. ----
    const int l15 = lane & 15;
    const int quad = lane >> 4;
    f32x4 acc[CTW];
#pragma unroll
    for (int c = 0; c < CTW; c++) acc[c] = (f32x4){0.f, 0.f, 0.f, 0.f};

#pragma unroll
    for (int kcg = 0; kcg < 4; kcg++) {
        const int k8 = kcg * 4 + quad;
        bf16x8 a = *(const bf16x8*)&Atile[(k8 * 16 + (l15 ^ k8)) * 8];
#pragma unroll
        for (int c = 0; c < CTW; c++) {
            const int ct = wv * CTW + c;
            bf16x8 b = *(const bf16x8*)&Wlds[(k8 * COUT + ct * 16 + (l15 ^ k8)) * 8];
            acc[c] = __builtin_amdgcn_mfma_f32_16x16x32_bf16(a, b, acc[c], 0, 0, 0);
        }
    }

#pragma unroll
    for (int rr = 0; rr < 4; rr++) {
        const int row = quad * 4 + rr;   // C row = (lane>>4)*4 + reg
        if (row < 8) {
            const int m = blockIdx.x * 8 + row;
            const float dv = dinv[m];
#pragma unroll
            for (int c = 0; c < CTW; c++) {
                const int ct = wv * CTW + c;
                Hn[(size_t)m * COUT + ct * 16 + l15] = f2bf(acc[c][rr] * dv);
            }
        }
    }

    // zero the pad row (row N_NODES) consumed by the next gather
    if (blockIdx.x == 0 && t < COUT / 4)
        *(unsigned long long*)((char*)Hn + (size_t)N_NODES * (COUT * 2) + t * 8) = 0ull;
}

// ---------------- pair aggregation C=64 + log_softmax (R8 version) ---------
__global__ __launch_bounds__(256) void aggregate64_lsm_pair(
    const unsigned short* __restrict__ Hb, const int* __restrict__ rowptr,
    const int* __restrict__ deg, const int* __restrict__ csr,
    const float* __restrict__ dinv, const float* __restrict__ bias,
    float* __restrict__ out) {
    const int lane = threadIdx.x & 63;
    const int wv = threadIdx.x >> 6;
    const int li = lane & 31;
    const int half = lane >> 5;
    const int n = blockIdx.x * 8 + wv * 2 + half;
    const unsigned li4 = (unsigned)li * 4u;
    const char* Hc = (const char*)Hb;

    unsigned s = *(const unsigned*)(Hc + (size_t)n * 128u + li4);
    float a0 = bf_lo(s), a1 = bf_hi(s);

    const int start = rowptr[n];
    const int dc = deg[n];
    const int dmax = max(dc, __shfl_xor(dc, 32));

    for (int eb = 0; eb < dmax; eb += 32) {
        int myidx = N_NODES;
        if (eb + li < dc) myidx = csr[start + eb + li];
        const int jmax = min(32, dmax - eb);
        int j = 0;
        for (; j + 16 <= jmax; j += 16) {
            int idx[16];
            unsigned u[16];
#pragma unroll
            for (int q = 0; q < 16; q++) idx[q] = __shfl(myidx, j + q, 32);
#pragma unroll
            for (int q = 0; q < 16; q++)
                u[q] = *(const unsigned*)(Hc + (((unsigned)idx[q] << 7) + li4));
#pragma unroll
            for (int q = 0; q < 16; q++) { a0 += bf_lo(u[q]); a1 += bf_hi(u[q]); }
        }
        for (; j + 8 <= jmax; j += 8) {
            int idx[8];
            unsigned u[8];
#pragma unroll
            for (int q = 0; q < 8; q++) idx[q] = __shfl(myidx, j + q, 32);
#pragma unroll
            for (int q = 0; q < 8; q++)
                u[q] = *(const unsigned*)(Hc + (((unsigned)idx[q] << 7) + li4));
#pragma unroll
            for (int q = 0; q < 8; q++) { a0 += bf_lo(u[q]); a1 += bf_hi(u[q]); }
        }
        for (; j + 4 <= jmax; j += 4) {
            int idx[4];
            unsigned u[4];
#pragma unroll
            for (int q = 0; q < 4; q++) idx[q] = __shfl(myidx, j + q, 32);
#pragma unroll
            for (int q = 0; q < 4; q++)
                u[q] = *(const unsigned*)(Hc + (((unsigned)idx[q] << 7) + li4));
#pragma unroll
            for (int q = 0; q < 4; q++) { a0 += bf_lo(u[q]); a1 += bf_hi(u[q]); }
        }
        for (; j < jmax; j++) {
            int i0 = __shfl(myidx, j, 32);
            unsigned u0 = *(const unsigned*)(Hc + (((unsigned)i0 << 7) + li4));
            a0 += bf_lo(u0); a1 += bf_hi(u0);
        }
    }

    const float dn = dinv[n];
    float2 bv = *(const float2*)((const char*)bias + li * 8);
    float v0 = a0 * dn + bv.x;
    float v1 = a1 * dn + bv.y;

    float m = fmaxf(v0, v1);
#pragma unroll
    for (int off = 16; off; off >>= 1) m = fmaxf(m, __shfl_xor(m, off));
    float e = expf(v0 - m) + expf(v1 - m);
#pragma unroll
    for (int off = 16; off; off >>= 1) e += __shfl_xor(e, off);
    float lse = m + logf(e);
    float2 o = make_float2(v0 - lse, v1 - lse);
    *(float2*)((char*)out + (size_t)n * 256 + li * 8) = o;
}

// ---------------------------------------------------------------------------
extern "C" void kernel_launch(void* const* d_in, const int* in_sizes, int n_in,
                              void* d_out, int out_size, void* d_ws, size_t ws_size,
                              hipStream_t stream) {
    const float* x = (const float*)d_in[0];
    const void* ei = d_in[1];
    const float* W1 = (const float*)d_in[2];
    const float* b1 = (const float*)d_in[3];
    const float* W2 = (const float*)d_in[4];
    const float* b2 = (const float*)d_in[5];
    const float* W3 = (const float*)d_in[6];
    const float* b3 = (const float*)d_in[7];
    float* out = (float*)d_out;

    char* w = (char*)d_ws;
    size_t off = 0;
    auto take = [&](size_t bytes) {
        char* p = w + off;
        off = (off + bytes + 255) & ~(size_t)255;
        return p;
    };
    int* flag = (int*)take(4);
    int* cursorPad = (int*)take((size_t)NB * 64);
    int* deg = (int*)take((size_t)N_NODES * 4);
    int* rowptr = (int*)take((size_t)N_NODES * 4);
    float* dinv = (float*)take((size_t)N_NODES * 4);
    int* csr = (int*)take((size_t)NB * BCAP * 4);            // padded CSR, 8 MB
    unsigned short* WT1 = (unsigned short*)take(128 * 128 * 2);
    unsigned short* WT2 = (unsigned short*)take(128 * 128 * 2);
    unsigned short* WT3 = (unsigned short*)take(64 * 128 * 2);
    unsigned short* A = (unsigned short*)take((size_t)(N_NODES + 1) * 128 * 2);
    unsigned short* B = (unsigned short*)take((size_t)(N_NODES + 1) * 128 * 2);
    unsigned* pairs = (unsigned*)A;   // 8 MB aliases A; dead before 1st GEMM

    prep_wt_kernel<<<4, 256, 0, stream>>>(W1, W2, W3, WT1, WT2, WT3,
                                          (const int*)ei, flag, cursorPad);
    scatter_direct<<<NCHUNK, 256, 0, stream>>>(ei, flag, cursorPad, pairs);
    fine_sort_kernel<<<NB, 256, 0, stream>>>(pairs, cursorPad, csr, rowptr, deg, dinv);

    const int gg = (N_NODES + 63) / 64;   // 1563; block 1562 covers pad row 100000
    const int g8 = N_NODES / 8;           // 12500, exact

    // layer 1 GEMM (fp32 X)
    gemm_mfma_f32<128><<<gg, 256, 0, stream>>>(x, WT1, dinv, A);
    // layer-1 aggregation fused with layer-2 GEMM:  B = (relu(agg(A)+b1) @ W2)*dinv
    agg128_fused<128><<<g8, 256, 0, stream>>>(A, rowptr, deg, csr, dinv, b1, WT2, B);
    // layer-2 aggregation fused with layer-3 GEMM:  A = (relu(agg(B)+b2) @ W3)*dinv
    agg128_fused<64><<<g8, 256, 0, stream>>>(B, rowptr, deg, csr, dinv, b2, WT3, A);
    // layer-3 aggregation + log_softmax
    aggregate64_lsm_pair<<<g8, 256, 0, stream>>>(A, rowptr, deg, csr, dinv, b3, out);
}

// Round 4
// 367.528 us; speedup vs baseline: 1.0304x; 1.0304x over previous
//
#include <hip/hip_runtime.h>
#include <hip/hip_bf16.h>

// GCN: 3x (GEMM + D^-1/2 (A+I) D^-1/2 aggregation) + log_softmax.
// R14: persistent fused agg+GEMM blocks. R13 post-mortem: per-block W^T
//      staging (12500 x 32KB) DOUBLED the L2 line-request load that bounds
//      the gather (61.5->96.2us, x1.56; FETCH_SIZE flat => requests not
//      HBM). Fix: grid-stride persistent blocks sized to residency
//      (<128>: 36KB LDS -> 4/CU -> 1024 blocks; <64>: 20KB -> 8/CU ->
//      2048), staging W^T ONCE per block (-92% W^T requests). Gather body
//      and MFMA epilogue byte-identical to R13 (passed, absmax 0.03125).

constexpr int N_NODES = 100000;
constexpr int E_EDGES = 1600000;
constexpr int NB = (N_NODES + 127) / 128;   // 782 coarse buckets
constexpr int BCAP = 2560;                  // bucket cap (mean 2048, sd 45)
constexpr int CHUNK = 4096;
constexpr int NCHUNK = (E_EDGES + CHUNK - 1) / CHUNK;  // 391
constexpr int NGRP = N_NODES / 8;           // 12500 node-groups

typedef short bf16x8 __attribute__((ext_vector_type(8)));
typedef float f32x4 __attribute__((ext_vector_type(4)));

// ---------------- helpers ---------------------------------------------------
__device__ __forceinline__ unsigned short f2bf(float f) {   // RNE fp32->bf16
    unsigned u = __float_as_uint(f);
    unsigned r = (u + 0x7fff + ((u >> 16) & 1)) >> 16;
    return (unsigned short)r;
}
__device__ __forceinline__ float bf_lo(unsigned u) { return __uint_as_float(u << 16); }
__device__ __forceinline__ float bf_hi(unsigned u) { return __uint_as_float(u & 0xffff0000u); }
__device__ __forceinline__ unsigned pack2bf(float lo, float hi) {
    return (unsigned)f2bf(lo) | ((unsigned)f2bf(hi) << 16);
}

__device__ __forceinline__ int get_idx(const void* ei, int use64, long long pos) {
    if (use64) return (int)((const long long*)ei)[pos];
    return ((const int*)ei)[pos];
}

// ---------------- W^T prep + detect + cursor zero (block 3) ----------------
__global__ void prep_wt_kernel(const float* __restrict__ W1, const float* __restrict__ W2,
                               const float* __restrict__ W3,
                               unsigned short* __restrict__ WT1,
                               unsigned short* __restrict__ WT2,
                               unsigned short* __restrict__ WT3,
                               const int* __restrict__ ei32, int* __restrict__ flag,
                               int* __restrict__ cursorPad) {
    const int b = blockIdx.x;
    if (b == 3) {
        for (int i = threadIdx.x; i < NB * 16; i += blockDim.x) cursorPad[i] = 0;
        if (threadIdx.x == 0) {
            int ok64 = 1;
#pragma unroll
            for (int i = 1; i < 64; i += 2) ok64 &= (ei32[i] == 0);
            *flag = ok64;
        }
        return;
    }
    const float* W = (b == 0) ? W1 : (b == 1) ? W2 : W3;
    unsigned short* WT = (b == 0) ? WT1 : (b == 1) ? WT2 : WT3;
    const int COUT = (b == 2) ? 64 : 128;
    for (int i = threadIdx.x; i < COUT * 128; i += blockDim.x) {
        int c = i >> 7;
        int k = i & 127;
        WT[c * 128 + k] = f2bf(W[k * COUT + c]);
    }
}

// ---------------- P1: single-pass scatter into fixed-capacity buckets ------
__global__ __launch_bounds__(256) void scatter_direct(
    const void* __restrict__ ei, const int* __restrict__ flag,
    int* __restrict__ cursorPad, unsigned* __restrict__ pairs) {
    __shared__ int h[NB];
    __shared__ int base[NB];
    __shared__ unsigned dstb[CHUNK];
    const int t = threadIdx.x;
    const int use64 = *flag;
    const int e0 = blockIdx.x * CHUNK;
    const int e1 = min(E_EDGES, e0 + CHUNK);

    for (int i = t; i < NB; i += 256) h[i] = 0;
    __syncthreads();
    for (int e = e0 + t; e < e1; e += 256) {
        unsigned d = (unsigned)get_idx(ei, use64, (long long)E_EDGES + e);
        dstb[e - e0] = d;
        atomicAdd(&h[d >> 7], 1);
    }
    __syncthreads();
    for (int i = t; i < NB; i += 256) {
        int c = h[i];
        if (c) base[i] = atomicAdd(&cursorPad[i * 16], c);
        h[i] = 0;
    }
    __syncthreads();
    for (int e = e0 + t; e < e1; e += 256) {
        unsigned s = (unsigned)get_idx(ei, use64, e);
        unsigned d = dstb[e - e0];
        int b = d >> 7;
        int r = base[b] + atomicAdd(&h[b], 1);
        if (r < BCAP) pairs[(unsigned)b * BCAP + r] = (s << 7) | (d & 127u);
    }
}

// ---------------- P2: per-bucket fine counting sort ------------------------
__global__ __launch_bounds__(256) void fine_sort_kernel(
    const unsigned* __restrict__ pairs, const int* __restrict__ cursorPad,
    int* __restrict__ csr, int* __restrict__ rowptr, int* __restrict__ deg,
    float* __restrict__ dinv) {
    __shared__ int h[128];
    __shared__ int rp[128];
    __shared__ int sc[128];
    const int t = threadIdx.x;
    const int b = blockIdx.x;
    const int base = b * BCAP;
    const int cnt = min(cursorPad[b * 16], BCAP);

    if (t < 128) h[t] = 0;
    __syncthreads();
    for (int i = t; i < cnt; i += 256) {
        unsigned p = pairs[base + i];
        atomicAdd(&h[p & 127u], 1);
    }
    __syncthreads();
    int v = (t < 128) ? h[t] : 0;
    if (t < 128) sc[t] = v;
    __syncthreads();
    int incl = v;
    for (int off = 1; off < 128; off <<= 1) {
        int add = (t >= off && t < 128) ? sc[t - off] : 0;
        __syncthreads();
        if (t < 128) {
            incl += add;
            sc[t] = incl;
        }
        __syncthreads();
    }
    if (t < 128) {
        rp[t] = incl - v;
        int node = b * 128 + t;
        if (node < N_NODES) {
            rowptr[node] = base + incl - v;
            deg[node] = v;
            dinv[node] = rsqrtf((float)(v + 1));
        }
        h[t] = 0;
    }
    __syncthreads();
    for (int i = t; i < cnt; i += 256) {
        unsigned p = pairs[base + i];
        int l = (int)(p & 127u);
        int r = atomicAdd(&h[l], 1);
        csr[base + rp[l] + r] = (int)(p >> 7);
    }
}

// ---------------- MFMA GEMM, fp32 input, XOR-swizzled LDS (layer 1) --------
// A slot (16B units): ((m>>4)*16 + k8)*16 + ((m&15) ^ k8)   [write 2-way]
// W slot:             (k8*COUT + ct*16 + (n16 ^ k8))        [write 2-way]
template <int COUT>
__global__ __launch_bounds__(256) void gemm_mfma_f32(const float* __restrict__ X,
                                                     const unsigned short* __restrict__ WT,
                                                     const float* __restrict__ dinv,
                                                     unsigned short* __restrict__ H) {
    constexpr int NT = COUT / 16;
    __shared__ short Albs[64 * 128];
    __shared__ short Wlds[COUT * 128];

    const int t = threadIdx.x;
    const int row0 = blockIdx.x * 64;

    for (int i = t; i < COUT * 16; i += 256) {
        int n = i >> 4, k8 = i & 15;
        bf16x8 v = *(const bf16x8*)&WT[n * 128 + k8 * 8];
        int ns = (n & ~15) | ((n & 15) ^ k8);
        *(bf16x8*)&Wlds[(k8 * COUT + ns) * 8] = v;
    }
    for (int i = t; i < 1024; i += 256) {
        int m = i >> 4, k8 = i & 15;
        int gr = min(row0 + m, N_NODES - 1);
        const float* p = &X[(size_t)gr * 128 + k8 * 8];
        float4 f0 = *(const float4*)p;
        float4 f1 = *(const float4*)(p + 4);
        bf16x8 v;
        v[0] = (short)f2bf(f0.x); v[1] = (short)f2bf(f0.y);
        v[2] = (short)f2bf(f0.z); v[3] = (short)f2bf(f0.w);
        v[4] = (short)f2bf(f1.x); v[5] = (short)f2bf(f1.y);
        v[6] = (short)f2bf(f1.z); v[7] = (short)f2bf(f1.w);
        int u = ((m >> 4) * 16 + k8) * 16 + ((m & 15) ^ k8);
        *(bf16x8*)&Albs[u * 8] = v;
    }
    __syncthreads();

    const int lane = t & 63;
    const int wv = t >> 6;
    const int l15 = lane & 15;
    const int quad = lane >> 4;

    f32x4 acc[NT];
#pragma unroll
    for (int ct = 0; ct < NT; ct++) acc[ct] = (f32x4){0.f, 0.f, 0.f, 0.f};

#pragma unroll
    for (int kcg = 0; kcg < 4; kcg++) {
        const int k8 = kcg * 4 + quad;
        bf16x8 a = *(const bf16x8*)&Albs[((wv * 16 + k8) * 16 + (l15 ^ k8)) * 8];
#pragma unroll
        for (int ct = 0; ct < NT; ct++) {
            bf16x8 b = *(const bf16x8*)&Wlds[(k8 * COUT + ct * 16 + (l15 ^ k8)) * 8];
            acc[ct] = __builtin_amdgcn_mfma_f32_16x16x32_bf16(a, b, acc[ct], 0, 0, 0);
        }
    }

    const int m0 = row0 + wv * 16;
#pragma unroll
    for (int r = 0; r < 4; r++) {
        int m = m0 + quad * 4 + r;
        if (m < N_NODES) {
            float dv = dinv[m];
#pragma unroll
            for (int ct = 0; ct < NT; ct++)
                H[(size_t)m * COUT + ct * 16 + l15] = f2bf(acc[ct][r] * dv);
        } else if (m == N_NODES) {
#pragma unroll
            for (int ct = 0; ct < NT; ct++)
                H[(size_t)m * COUT + ct * 16 + l15] = 0;
        }
    }
}

// ---------------- persistent fused: pair aggregation + next-layer GEMM -----
// W^T staged swizzled ONCE per resident block; grid-stride loop over the
// 12500 node-groups. Gather body = R10's proven 32-lane pair code; epilogue
// = R13's verified MFMA (16-row A-tile, rows 8..15 zero, XOR swizzle).
template <int COUT>
__global__ __launch_bounds__(256) void agg128_fused_p(
    const unsigned short* __restrict__ Hb, const int* __restrict__ rowptr,
    const int* __restrict__ deg, const int* __restrict__ csr,
    const float* __restrict__ dinv, const float* __restrict__ bias,
    const unsigned short* __restrict__ WT, unsigned short* __restrict__ Hn) {
    constexpr int NT = COUT / 16;   // 8 or 4 column tiles
    constexpr int CTW = NT / 4;     // ct per wave: 2 or 1
    __shared__ short Wlds[COUT * 128];
    __shared__ short Atile[16 * 128];

    const int t = threadIdx.x;

    // stage W^T swizzled, once per block
    for (int i = t; i < COUT * 16; i += 256) {
        int nn = i >> 4, k8 = i & 15;
        bf16x8 v = *(const bf16x8*)&WT[nn * 128 + k8 * 8];
        int ns = (nn & ~15) | ((nn & 15) ^ k8);
        *(bf16x8*)&Wlds[(k8 * COUT + ns) * 8] = v;
    }
    // zero A-tile rows 8..15 once (XOR swizzle keeps row-sets 0..7 / 8..15
    // in disjoint slots, so the per-group live writes never touch these)
    if (t < 128) {
        int k8z = t >> 3, mm = 8 + (t & 7);
        *(uint4*)&Atile[(k8z * 16 + (mm ^ k8z)) * 8] = (uint4){0u, 0u, 0u, 0u};
    }
    // zero the pad row (row N_NODES) consumed by the next kernel's gather
    if (blockIdx.x == 0 && t < COUT / 4)
        *(unsigned long long*)((char*)Hn + (size_t)N_NODES * (COUT * 2) + t * 8) = 0ull;

    const int lane = t & 63;
    const int wv = t >> 6;
    const int li = lane & 31;
    const int half = lane >> 5;
    const unsigned li8 = (unsigned)li * 8u;
    const char* Hc = (const char*)Hb;
    const int l15 = lane & 15;
    const int quad = lane >> 4;

    __syncthreads();   // Wlds + Atile zeros visible

    for (int g = blockIdx.x; g < NGRP; g += gridDim.x) {
        const int n = g * 8 + wv * 2 + half;   // N % 8 == 0

        uint2 s = *(const uint2*)(Hc + (size_t)n * 256u + li8);  // self loop
        float a0 = bf_lo(s.x), a1 = bf_hi(s.x), a2 = bf_lo(s.y), a3 = bf_hi(s.y);

        const int start = rowptr[n];
        const int dc = deg[n];
        const int dmax = max(dc, __shfl_xor(dc, 32));

        for (int eb = 0; eb < dmax; eb += 32) {
            int myidx = N_NODES;                     // pad row (zeros)
            if (eb + li < dc) myidx = csr[start + eb + li];
            const int jmax = min(32, dmax - eb);
            int j = 0;
            for (; j + 16 <= jmax; j += 16) {
                int idx[16];
                uint2 u[16];
#pragma unroll
                for (int q = 0; q < 16; q++) idx[q] = __shfl(myidx, j + q, 32);
#pragma unroll
                for (int q = 0; q < 16; q++)
                    u[q] = *(const uint2*)(Hc + (((unsigned)idx[q] << 8) + li8));
#pragma unroll
                for (int q = 0; q < 16; q++) {
                    a0 += bf_lo(u[q].x); a1 += bf_hi(u[q].x);
                    a2 += bf_lo(u[q].y); a3 += bf_hi(u[q].y);
                }
            }
            for (; j + 8 <= jmax; j += 8) {
                int idx[8];
                uint2 u[8];
#pragma unroll
                for (int q = 0; q < 8; q++) idx[q] = __shfl(myidx, j + q, 32);
#pragma unroll
                for (int q = 0; q < 8; q++)
                    u[q] = *(const uint2*)(Hc + (((unsigned)idx[q] << 8) + li8));
#pragma unroll
                for (int q = 0; q < 8; q++) {
                    a0 += bf_lo(u[q].x); a1 += bf_hi(u[q].x);
                    a2 += bf_lo(u[q].y); a3 += bf_hi(u[q].y);
                }
            }
            for (; j + 4 <= jmax; j += 4) {
                int idx[4];
                uint2 u[4];
#pragma unroll
                for (int q = 0; q < 4; q++) idx[q] = __shfl(myidx, j + q, 32);
#pragma unroll
                for (int q = 0; q < 4; q++)
                    u[q] = *(const uint2*)(Hc + (((unsigned)idx[q] << 8) + li8));
#pragma unroll
                for (int q = 0; q < 4; q++) {
                    a0 += bf_lo(u[q].x); a1 += bf_hi(u[q].x);
                    a2 += bf_lo(u[q].y); a3 += bf_hi(u[q].y);
                }
            }
            for (; j < jmax; j++) {
                int i0 = __shfl(myidx, j, 32);
                uint2 u0 = *(const uint2*)(Hc + (((unsigned)i0 << 8) + li8));
                a0 += bf_lo(u0.x); a1 += bf_hi(u0.x);
                a2 += bf_lo(u0.y); a3 += bf_hi(u0.y);
            }
        }

        // bias+relu -> swizzled A-tile row r, cols 4li..4li+3
        {
            const float dn = dinv[n];
            float4 bv = *(const float4*)((const char*)bias + li * 16);
            unsigned w0 = pack2bf(fmaxf(a0 * dn + bv.x, 0.f), fmaxf(a1 * dn + bv.y, 0.f));
            unsigned w1 = pack2bf(fmaxf(a2 * dn + bv.z, 0.f), fmaxf(a3 * dn + bv.w, 0.f));
            const int r = wv * 2 + half;     // 0..7
            const int k8 = li >> 1;          // slot column group
            uint2 o; o.x = w0; o.y = w1;
            *(uint2*)&Atile[(k8 * 16 + (r ^ k8)) * 8 + (li & 1) * 4] = o;
        }
        __syncthreads();

        // 16x128 @ 128xCOUT (rows 8..15 zero); wave wv owns ct=wv*CTW..
        f32x4 acc[CTW];
#pragma unroll
        for (int c = 0; c < CTW; c++) acc[c] = (f32x4){0.f, 0.f, 0.f, 0.f};

#pragma unroll
        for (int kcg = 0; kcg < 4; kcg++) {
            const int k8 = kcg * 4 + quad;
            bf16x8 a = *(const bf16x8*)&Atile[(k8 * 16 + (l15 ^ k8)) * 8];
#pragma unroll
            for (int c = 0; c < CTW; c++) {
                const int ct = wv * CTW + c;
                bf16x8 b = *(const bf16x8*)&Wlds[(k8 * COUT + ct * 16 + (l15 ^ k8)) * 8];
                acc[c] = __builtin_amdgcn_mfma_f32_16x16x32_bf16(a, b, acc[c], 0, 0, 0);
            }
        }

#pragma unroll
        for (int rr = 0; rr < 4; rr++) {
            const int row = quad * 4 + rr;   // C row = (lane>>4)*4 + reg
            if (row < 8) {
                const int m = g * 8 + row;
                const float dv = dinv[m];
#pragma unroll
                for (int c = 0; c < CTW; c++) {
                    const int ct = wv * CTW + c;
                    Hn[(size_t)m * COUT + ct * 16 + l15] = f2bf(acc[c][rr] * dv);
                }
            }
        }
        __syncthreads();   // Atile reads done before next group's writes
    }
}

// ---------------- pair aggregation C=64 + log_softmax (R8 version) ---------
__global__ __launch_bounds__(256) void aggregate64_lsm_pair(
    const unsigned short* __restrict__ Hb, const int* __restrict__ rowptr,
    const int* __restrict__ deg, const int* __restrict__ csr,
    const float* __restrict__ dinv, const float* __restrict__ bias,
    float* __restrict__ out) {
    const int lane = threadIdx.x & 63;
    const int wv = threadIdx.x >> 6;
    const int li = lane & 31;
    const int half = lane >> 5;
    const int n = blockIdx.x * 8 + wv * 2 + half;
    const unsigned li4 = (unsigned)li * 4u;
    const char* Hc = (const char*)Hb;

    unsigned s = *(const unsigned*)(Hc + (size_t)n * 128u + li4);
    float a0 = bf_lo(s), a1 = bf_hi(s);

    const int start = rowptr[n];
    const int dc = deg[n];
    const int dmax = max(dc, __shfl_xor(dc, 32));

    for (int eb = 0; eb < dmax; eb += 32) {
        int myidx = N_NODES;
        if (eb + li < dc) myidx = csr[start + eb + li];
        const int jmax = min(32, dmax - eb);
        int j = 0;
        for (; j + 16 <= jmax; j += 16) {
            int idx[16];
            unsigned u[16];
#pragma unroll
            for (int q = 0; q < 16; q++) idx[q] = __shfl(myidx, j + q, 32);
#pragma unroll
            for (int q = 0; q < 16; q++)
                u[q] = *(const unsigned*)(Hc + (((unsigned)idx[q] << 7) + li4));
#pragma unroll
            for (int q = 0; q < 16; q++) { a0 += bf_lo(u[q]); a1 += bf_hi(u[q]); }
        }
        for (; j + 8 <= jmax; j += 8) {
            int idx[8];
            unsigned u[8];
#pragma unroll
            for (int q = 0; q < 8; q++) idx[q] = __shfl(myidx, j + q, 32);
#pragma unroll
            for (int q = 0; q < 8; q++)
                u[q] = *(const unsigned*)(Hc + (((unsigned)idx[q] << 7) + li4));
#pragma unroll
            for (int q = 0; q < 8; q++) { a0 += bf_lo(u[q]); a1 += bf_hi(u[q]); }
        }
        for (; j + 4 <= jmax; j += 4) {
            int idx[4];
            unsigned u[4];
#pragma unroll
            for (int q = 0; q < 4; q++) idx[q] = __shfl(myidx, j + q, 32);
#pragma unroll
            for (int q = 0; q < 4; q++)
                u[q] = *(const unsigned*)(Hc + (((unsigned)idx[q] << 7) + li4));
#pragma unroll
            for (int q = 0; q < 4; q++) { a0 += bf_lo(u[q]); a1 += bf_hi(u[q]); }
        }
        for (; j < jmax; j++) {
            int i0 = __shfl(myidx, j, 32);
            unsigned u0 = *(const unsigned*)(Hc + (((unsigned)i0 << 7) + li4));
            a0 += bf_lo(u0); a1 += bf_hi(u0);
        }
    }

    const float dn = dinv[n];
    float2 bv = *(const float2*)((const char*)bias + li * 8);
    float v0 = a0 * dn + bv.x;
    float v1 = a1 * dn + bv.y;

    float m = fmaxf(v0, v1);
#pragma unroll
    for (int off = 16; off; off >>= 1) m = fmaxf(m, __shfl_xor(m, off));
    float e = expf(v0 - m) + expf(v1 - m);
#pragma unroll
    for (int off = 16; off; off >>= 1) e += __shfl_xor(e, off);
    float lse = m + logf(e);
    float2 o = make_float2(v0 - lse, v1 - lse);
    *(float2*)((char*)out + (size_t)n * 256 + li * 8) = o;
}

// ---------------------------------------------------------------------------
extern "C" void kernel_launch(void* const* d_in, const int* in_sizes, int n_in,
                              void* d_out, int out_size, void* d_ws, size_t ws_size,
                              hipStream_t stream) {
    const float* x = (const float*)d_in[0];
    const void* ei = d_in[1];
    const float* W1 = (const float*)d_in[2];
    const float* b1 = (const float*)d_in[3];
    const float* W2 = (const float*)d_in[4];
    const float* b2 = (const float*)d_in[5];
    const float* W3 = (const float*)d_in[6];
    const float* b3 = (const float*)d_in[7];
    float* out = (float*)d_out;

    char* w = (char*)d_ws;
    size_t off = 0;
    auto take = [&](size_t bytes) {
        char* p = w + off;
        off = (off + bytes + 255) & ~(size_t)255;
        return p;
    };
    int* flag = (int*)take(4);
    int* cursorPad = (int*)take((size_t)NB * 64);
    int* deg = (int*)take((size_t)N_NODES * 4);
    int* rowptr = (int*)take((size_t)N_NODES * 4);
    float* dinv = (float*)take((size_t)N_NODES * 4);
    int* csr = (int*)take((size_t)NB * BCAP * 4);            // padded CSR, 8 MB
    unsigned short* WT1 = (unsigned short*)take(128 * 128 * 2);
    unsigned short* WT2 = (unsigned short*)take(128 * 128 * 2);
    unsigned short* WT3 = (unsigned short*)take(64 * 128 * 2);
    unsigned short* A = (unsigned short*)take((size_t)(N_NODES + 1) * 128 * 2);
    unsigned short* B = (unsigned short*)take((size_t)(N_NODES + 1) * 128 * 2);
    unsigned* pairs = (unsigned*)A;   // 8 MB aliases A; dead before 1st GEMM

    prep_wt_kernel<<<4, 256, 0, stream>>>(W1, W2, W3, WT1, WT2, WT3,
                                          (const int*)ei, flag, cursorPad);
    scatter_direct<<<NCHUNK, 256, 0, stream>>>(ei, flag, cursorPad, pairs);
    fine_sort_kernel<<<NB, 256, 0, stream>>>(pairs, cursorPad, csr, rowptr, deg, dinv);

    const int gg = (N_NODES + 63) / 64;   // 1563; block 1562 covers pad row 100000
    const int g8 = N_NODES / 8;           // 12500

    // layer 1 GEMM (fp32 X)
    gemm_mfma_f32<128><<<gg, 256, 0, stream>>>(x, WT1, dinv, A);
    // layer-1 agg fused with layer-2 GEMM (persistent): 36KB LDS -> 4/CU
    agg128_fused_p<128><<<1024, 256, 0, stream>>>(A, rowptr, deg, csr, dinv, b1, WT2, B);
    // layer-2 agg fused with layer-3 GEMM (persistent): 20KB LDS -> 8/CU
    agg128_fused_p<64><<<2048, 256, 0, stream>>>(B, rowptr, deg, csr, dinv, b2, WT3, A);
    // layer-3 aggregation + log_softmax
    aggregate64_lsm_pair<<<g8, 256, 0, stream>>>(A, rowptr, deg, csr, dinv, b3, out);
}